// Round 3
// baseline (312.926 us; speedup 1.0000x reference)
//
#include <hip/hip_runtime.h>
#include <hip/hip_cooperative_groups.h>
#include <math.h>

namespace cg = cooperative_groups;

#define B_     32
#define S_     1024
#define H2_    1024
#define TOPIC_ 256
#define NTHR   256
#define WORK1  2048   // phase-1 work items: 32 b x 64 h-tiles of 16
#define WORK2  2048   // phase-2 work items: 32768 rows / 16 rows per block

__device__ __forceinline__ float fast_tanh(float x) {
    // tanh(x) = 1 - 2/(exp(2x)+1); saturates to +-1 at extremes.
    float e = __expf(2.0f * x);
    return 1.0f - 2.0f / (e + 1.0f);
}

__global__ __launch_bounds__(NTHR, 8) void fused_kernel(
    const float* __restrict__ enc,       // [B, S, H2]
    const int*   __restrict__ mask,      // [B, S]
    const float* __restrict__ s,         // [B, H2]
    const float* __restrict__ coverage,  // [B, S]
    const float* __restrict__ hz,        // [B, TOPIC]
    const float* __restrict__ W_s,       // [H2, H2]
    const float* __restrict__ W_c,       // [H2]
    const float* __restrict__ b_c,       // [H2]
    const float* __restrict__ W_z,       // [TOPIC, H2]
    const float* __restrict__ v,         // [H2]
    float* __restrict__ out_a,           // [B, S]
    float* __restrict__ out_cov,         // [B, S]
    float* __restrict__ combined,        // ws [B, H2]
    float* __restrict__ e_ws)            // ws [B, S]
{
    const int tid = threadIdx.x;
    cg::grid_group grid = cg::this_grid();

    __shared__ float sx[H2_];
    __shared__ float zx[TOPIC_];
    __shared__ float part[16][16];
    __shared__ float red[4];

    // ================= Phase 1: combined[b][h] = s@W_s + hz@W_z + b_c =======
    for (int wk = blockIdx.x; wk < WORK1; wk += gridDim.x) {
        const int b    = wk >> 6;          // 64 h-tiles per batch
        const int tile = wk & 63;
        const int hl   = tid & 15;
        const int kc   = tid >> 4;         // 0..15 K-chunks
        const int h    = tile * 16 + hl;

        for (int i = tid; i < H2_; i += NTHR)    sx[i] = s[b * H2_ + i];
        for (int i = tid; i < TOPIC_; i += NTHR) zx[i] = hz[b * TOPIC_ + i];
        __syncthreads();

        float a0 = 0.f, a1 = 0.f, a2 = 0.f, a3 = 0.f;
        {   // W_s: 64 k-rows per chunk; rotate start by 8*kc to spread LDS banks
            const int k0  = kc * 64;
            const int rot = (kc & 3) * 8;
            const float* Wp = W_s + (size_t)k0 * H2_ + h;
            #pragma unroll 4
            for (int i = 0; i < 64; i += 4) {
                const int j = (i + rot) & 63;   // rot%8==0 -> group of 4 never wraps
                a0 = fmaf(sx[k0 + j    ], Wp[(size_t)(j    ) * H2_], a0);
                a1 = fmaf(sx[k0 + j + 1], Wp[(size_t)(j + 1) * H2_], a1);
                a2 = fmaf(sx[k0 + j + 2], Wp[(size_t)(j + 2) * H2_], a2);
                a3 = fmaf(sx[k0 + j + 3], Wp[(size_t)(j + 3) * H2_], a3);
            }
        }
        {   // W_z: 16 j-rows per chunk
            const int j0  = kc * 16;
            const int rot = (kc & 3) * 4;
            const float* Wp = W_z + (size_t)j0 * H2_ + h;
            #pragma unroll
            for (int i = 0; i < 16; i += 4) {
                const int j = (i + rot) & 15;
                a0 = fmaf(zx[j0 + j    ], Wp[(size_t)(j    ) * H2_], a0);
                a1 = fmaf(zx[j0 + j + 1], Wp[(size_t)(j + 1) * H2_], a1);
                a2 = fmaf(zx[j0 + j + 2], Wp[(size_t)(j + 2) * H2_], a2);
                a3 = fmaf(zx[j0 + j + 3], Wp[(size_t)(j + 3) * H2_], a3);
            }
        }
        part[kc][hl] = (a0 + a1) + (a2 + a3);
        __syncthreads();
        if (tid < 16) {
            float r = b_c[tile * 16 + tid];
            #pragma unroll
            for (int c = 0; c < 16; ++c) r += part[c][tid];
            combined[b * H2_ + tile * 16 + tid] = r;
        }
        __syncthreads();   // protect sx/zx before next iteration refill
    }

    grid.sync();

    // ================= Phase 2: e[row] = sum_h tanh(enc+cov*Wc+comb)*v ======
    // 16 rows per work item; wave w handles 4 consecutive rows, in-wave reduce.
    for (int wk = blockIdx.x; wk < WORK2; wk += gridDim.x) {
        const int row0  = wk * 16;
        const int b     = row0 >> 10;            // all 16 rows share one batch
        const int wv    = tid >> 6;
        const int lane  = tid & 63;
        const int rbase = row0 + wv * 4;

        const float4* com4 = (const float4*)(combined + (size_t)b * H2_);
        const float4* wc4  = (const float4*)W_c;
        const float4* v4   = (const float4*)v;
        const float4* e4   = (const float4*)enc + (size_t)rbase * (H2_ / 4);

        const float cv0 = coverage[rbase    ];
        const float cv1 = coverage[rbase + 1];
        const float cv2 = coverage[rbase + 2];
        const float cv3 = coverage[rbase + 3];

        float ac0 = 0.f, ac1 = 0.f, ac2 = 0.f, ac3 = 0.f;

        #pragma unroll
        for (int i = 0; i < 4; ++i) {
            const int idx = lane + i * 64;       // float4 index within a row
            const float4 wc = wc4[idx];
            const float4 vv = v4[idx];
            const float4 cb = com4[idx];
            const float4 e0 = e4[idx];
            const float4 e1 = e4[256 + idx];
            const float4 e2 = e4[512 + idx];
            const float4 e3 = e4[768 + idx];

#define ROW_ACC(acc, ev, cv)                                           \
            acc = fmaf(fast_tanh(fmaf(cv, wc.x, ev.x) + cb.x), vv.x, acc); \
            acc = fmaf(fast_tanh(fmaf(cv, wc.y, ev.y) + cb.y), vv.y, acc); \
            acc = fmaf(fast_tanh(fmaf(cv, wc.z, ev.z) + cb.z), vv.z, acc); \
            acc = fmaf(fast_tanh(fmaf(cv, wc.w, ev.w) + cb.w), vv.w, acc);

            ROW_ACC(ac0, e0, cv0)
            ROW_ACC(ac1, e1, cv1)
            ROW_ACC(ac2, e2, cv2)
            ROW_ACC(ac3, e3, cv3)
#undef ROW_ACC
        }

        #pragma unroll
        for (int off = 32; off > 0; off >>= 1) {
            ac0 += __shfl_xor(ac0, off, 64);
            ac1 += __shfl_xor(ac1, off, 64);
            ac2 += __shfl_xor(ac2, off, 64);
            ac3 += __shfl_xor(ac3, off, 64);
        }
        if (lane == 0) {
            e_ws[rbase    ] = ac0;
            e_ws[rbase + 1] = ac1;
            e_ws[rbase + 2] = ac2;
            e_ws[rbase + 3] = ac3;
        }
    }

    grid.sync();

    // ================= Phase 3: masked softmax + next_coverage ==============
    for (int wk = blockIdx.x; wk < B_; wk += gridDim.x) {
        const int b = wk;

        float ev[4];
        #pragma unroll
        for (int i = 0; i < 4; ++i) {
            const int idx = b * S_ + tid * 4 + i;
            float e = e_ws[idx];
            if (mask[idx] == 0) e = -INFINITY;
            ev[i] = e;
        }

        float m = fmaxf(fmaxf(ev[0], ev[1]), fmaxf(ev[2], ev[3]));
        #pragma unroll
        for (int off = 1; off < 64; off <<= 1)
            m = fmaxf(m, __shfl_xor(m, off, 64));

        if ((tid & 63) == 0) red[tid >> 6] = m;
        __syncthreads();
        m = fmaxf(fmaxf(red[0], red[1]), fmaxf(red[2], red[3]));

        float p[4];
        float lsum = 0.0f;
        #pragma unroll
        for (int i = 0; i < 4; ++i) {
            p[i] = __expf(ev[i] - m);
            lsum += p[i];
        }
        #pragma unroll
        for (int off = 1; off < 64; off <<= 1)
            lsum += __shfl_xor(lsum, off, 64);

        __syncthreads();   // done reading red[] from max phase
        if ((tid & 63) == 0) red[tid >> 6] = lsum;
        __syncthreads();
        const float tot = red[0] + red[1] + red[2] + red[3];
        const float inv = 1.0f / tot;

        #pragma unroll
        for (int i = 0; i < 4; ++i) {
            const int idx = b * S_ + tid * 4 + i;
            const float a = p[i] * inv;
            out_a[idx]   = a;
            out_cov[idx] = coverage[idx] + a;
        }
        __syncthreads();
    }
}

extern "C" void kernel_launch(void* const* d_in, const int* in_sizes, int n_in,
                              void* d_out, int out_size, void* d_ws, size_t ws_size,
                              hipStream_t stream) {
    const float* enc      = (const float*)d_in[0];
    const int*   mask     = (const int*)  d_in[1];
    const float* s        = (const float*)d_in[2];
    const float* coverage = (const float*)d_in[3];
    const float* hz       = (const float*)d_in[4];
    const float* W_s      = (const float*)d_in[5];
    const float* W_c      = (const float*)d_in[6];
    const float* b_c      = (const float*)d_in[7];
    const float* W_z      = (const float*)d_in[8];
    const float* v        = (const float*)d_in[9];

    float* out_a   = (float*)d_out;            // [B, S]
    float* out_cov = out_a + B_ * S_;          // [B, S]

    float* combined = (float*)d_ws;            // [B, H2]
    float* e_ws     = combined + B_ * H2_;     // [B, S]

    // Cooperative-safe grid: min(work, occupancy * CU count); grid-stride
    // loops inside make any clamp correct.
    int maxb = 0;
    hipOccupancyMaxActiveBlocksPerMultiprocessor(
        &maxb, reinterpret_cast<const void*>(fused_kernel), NTHR, 0);
    if (maxb <= 0) maxb = 4;
    int dev = 0;
    hipGetDevice(&dev);
    hipDeviceProp_t prop;
    int ncu = 256;
    if (hipGetDeviceProperties(&prop, dev) == hipSuccess) ncu = prop.multiProcessorCount;
    int nblk = maxb * ncu;
    if (nblk > WORK1) nblk = WORK1;

    void* args[] = {
        (void*)&enc, (void*)&mask, (void*)&s, (void*)&coverage, (void*)&hz,
        (void*)&W_s, (void*)&W_c, (void*)&b_c, (void*)&W_z, (void*)&v,
        (void*)&out_a, (void*)&out_cov, (void*)&combined, (void*)&e_ws
    };
    hipLaunchCooperativeKernel(reinterpret_cast<const void*>(fused_kernel),
                               dim3(nblk), dim3(NTHR), args, 0, stream);
}

// Round 4
// 179.288 us; speedup vs baseline: 1.7454x; 1.7454x over previous
//
#include <hip/hip_runtime.h>
#include <hip/hip_cooperative_groups.h>
#include <math.h>

namespace cg = cooperative_groups;

#define B_     32
#define S_     1024
#define H2_    1024
#define TOPIC_ 256
#define NTHR   256
#define WORK1  2048   // phase-1 work items: 32 b x 64 h-tiles of 16
#define WORK2  2048   // phase-2 work items: 32768 rows / 16 rows per block

__device__ __forceinline__ float fast_tanh(float x) {
    // tanh(x) = 1 - 2/(exp(2x)+1); saturates to +-1 at extremes.
    float e = __expf(2.0f * x);
    return 1.0f - 2.0f / (e + 1.0f);
}

// min-waves/EU = 4 -> 128 VGPR cap: phase 2 holds ~28 live floats/thread,
// the round-3 cap of 32 VGPRs (min-waves=8) spilled 74 MB to scratch.
__global__ __launch_bounds__(NTHR, 4) void fused_kernel(
    const float* __restrict__ enc,       // [B, S, H2]
    const int*   __restrict__ mask,      // [B, S]
    const float* __restrict__ s,         // [B, H2]
    const float* __restrict__ coverage,  // [B, S]
    const float* __restrict__ hz,        // [B, TOPIC]
    const float* __restrict__ W_s,       // [H2, H2]
    const float* __restrict__ W_c,       // [H2]
    const float* __restrict__ b_c,       // [H2]
    const float* __restrict__ W_z,       // [TOPIC, H2]
    const float* __restrict__ v,         // [H2]
    float* __restrict__ out_a,           // [B, S]
    float* __restrict__ out_cov,         // [B, S]
    float* __restrict__ combined,        // ws [B, H2]
    float* __restrict__ e_ws)            // ws [B, S]
{
    const int tid = threadIdx.x;
    cg::grid_group grid = cg::this_grid();

    __shared__ float sx[H2_];
    __shared__ float zx[TOPIC_];
    __shared__ float part[16][16];
    __shared__ float red[4];

    // ================= Phase 1: combined[b][h] = s@W_s + hz@W_z + b_c =======
    for (int wk = blockIdx.x; wk < WORK1; wk += gridDim.x) {
        const int b    = wk >> 6;          // 64 h-tiles per batch
        const int tile = wk & 63;
        const int hl   = tid & 15;
        const int kc   = tid >> 4;         // 0..15 K-chunks
        const int h    = tile * 16 + hl;

        for (int i = tid; i < H2_; i += NTHR)    sx[i] = s[b * H2_ + i];
        for (int i = tid; i < TOPIC_; i += NTHR) zx[i] = hz[b * TOPIC_ + i];
        __syncthreads();

        float a0 = 0.f, a1 = 0.f, a2 = 0.f, a3 = 0.f;
        {   // W_s: 64 k-rows per chunk; rotate start by 8*kc to spread LDS banks
            const int k0  = kc * 64;
            const int rot = (kc & 3) * 8;
            const float* Wp = W_s + (size_t)k0 * H2_ + h;
            #pragma unroll 4
            for (int i = 0; i < 64; i += 4) {
                const int j = (i + rot) & 63;   // rot%8==0 -> group of 4 never wraps
                a0 = fmaf(sx[k0 + j    ], Wp[(size_t)(j    ) * H2_], a0);
                a1 = fmaf(sx[k0 + j + 1], Wp[(size_t)(j + 1) * H2_], a1);
                a2 = fmaf(sx[k0 + j + 2], Wp[(size_t)(j + 2) * H2_], a2);
                a3 = fmaf(sx[k0 + j + 3], Wp[(size_t)(j + 3) * H2_], a3);
            }
        }
        {   // W_z: 16 j-rows per chunk
            const int j0  = kc * 16;
            const int rot = (kc & 3) * 4;
            const float* Wp = W_z + (size_t)j0 * H2_ + h;
            #pragma unroll
            for (int i = 0; i < 16; i += 4) {
                const int j = (i + rot) & 15;
                a0 = fmaf(zx[j0 + j    ], Wp[(size_t)(j    ) * H2_], a0);
                a1 = fmaf(zx[j0 + j + 1], Wp[(size_t)(j + 1) * H2_], a1);
                a2 = fmaf(zx[j0 + j + 2], Wp[(size_t)(j + 2) * H2_], a2);
                a3 = fmaf(zx[j0 + j + 3], Wp[(size_t)(j + 3) * H2_], a3);
            }
        }
        part[kc][hl] = (a0 + a1) + (a2 + a3);
        __syncthreads();
        if (tid < 16) {
            float r = b_c[tile * 16 + tid];
            #pragma unroll
            for (int c = 0; c < 16; ++c) r += part[c][tid];
            combined[b * H2_ + tile * 16 + tid] = r;
        }
        __syncthreads();   // protect sx/zx before next iteration refill
    }

    grid.sync();

    // ================= Phase 2: e[row] = sum_h tanh(enc+cov*Wc+comb)*v ======
    // 16 rows per work item; wave w handles 4 consecutive rows, in-wave reduce.
    for (int wk = blockIdx.x; wk < WORK2; wk += gridDim.x) {
        const int row0  = wk * 16;
        const int b     = row0 >> 10;            // all 16 rows share one batch
        const int wv    = tid >> 6;
        const int lane  = tid & 63;
        const int rbase = row0 + wv * 4;

        const float4* com4 = (const float4*)(combined + (size_t)b * H2_);
        const float4* wc4  = (const float4*)W_c;
        const float4* v4   = (const float4*)v;
        const float4* e4   = (const float4*)enc + (size_t)rbase * (H2_ / 4);

        const float cv0 = coverage[rbase    ];
        const float cv1 = coverage[rbase + 1];
        const float cv2 = coverage[rbase + 2];
        const float cv3 = coverage[rbase + 3];

        float ac0 = 0.f, ac1 = 0.f, ac2 = 0.f, ac3 = 0.f;

        #pragma unroll
        for (int i = 0; i < 4; ++i) {
            const int idx = lane + i * 64;       // float4 index within a row
            const float4 wc = wc4[idx];
            const float4 vv = v4[idx];
            const float4 cb = com4[idx];
            const float4 e0 = e4[idx];
            const float4 e1 = e4[256 + idx];
            const float4 e2 = e4[512 + idx];
            const float4 e3 = e4[768 + idx];

#define ROW_ACC(acc, ev, cv)                                           \
            acc = fmaf(fast_tanh(fmaf(cv, wc.x, ev.x) + cb.x), vv.x, acc); \
            acc = fmaf(fast_tanh(fmaf(cv, wc.y, ev.y) + cb.y), vv.y, acc); \
            acc = fmaf(fast_tanh(fmaf(cv, wc.z, ev.z) + cb.z), vv.z, acc); \
            acc = fmaf(fast_tanh(fmaf(cv, wc.w, ev.w) + cb.w), vv.w, acc);

            ROW_ACC(ac0, e0, cv0)
            ROW_ACC(ac1, e1, cv1)
            ROW_ACC(ac2, e2, cv2)
            ROW_ACC(ac3, e3, cv3)
#undef ROW_ACC
        }

        #pragma unroll
        for (int off = 32; off > 0; off >>= 1) {
            ac0 += __shfl_xor(ac0, off, 64);
            ac1 += __shfl_xor(ac1, off, 64);
            ac2 += __shfl_xor(ac2, off, 64);
            ac3 += __shfl_xor(ac3, off, 64);
        }
        if (lane == 0) {
            e_ws[rbase    ] = ac0;
            e_ws[rbase + 1] = ac1;
            e_ws[rbase + 2] = ac2;
            e_ws[rbase + 3] = ac3;
        }
    }

    grid.sync();

    // ================= Phase 3: masked softmax + next_coverage ==============
    for (int wk = blockIdx.x; wk < B_; wk += gridDim.x) {
        const int b = wk;

        float ev[4];
        #pragma unroll
        for (int i = 0; i < 4; ++i) {
            const int idx = b * S_ + tid * 4 + i;
            float e = e_ws[idx];
            if (mask[idx] == 0) e = -INFINITY;
            ev[i] = e;
        }

        float m = fmaxf(fmaxf(ev[0], ev[1]), fmaxf(ev[2], ev[3]));
        #pragma unroll
        for (int off = 1; off < 64; off <<= 1)
            m = fmaxf(m, __shfl_xor(m, off, 64));

        if ((tid & 63) == 0) red[tid >> 6] = m;
        __syncthreads();
        m = fmaxf(fmaxf(red[0], red[1]), fmaxf(red[2], red[3]));

        float p[4];
        float lsum = 0.0f;
        #pragma unroll
        for (int i = 0; i < 4; ++i) {
            p[i] = __expf(ev[i] - m);
            lsum += p[i];
        }
        #pragma unroll
        for (int off = 1; off < 64; off <<= 1)
            lsum += __shfl_xor(lsum, off, 64);

        __syncthreads();   // done reading red[] from max phase
        if ((tid & 63) == 0) red[tid >> 6] = lsum;
        __syncthreads();
        const float tot = red[0] + red[1] + red[2] + red[3];
        const float inv = 1.0f / tot;

        #pragma unroll
        for (int i = 0; i < 4; ++i) {
            const int idx = b * S_ + tid * 4 + i;
            const float a = p[i] * inv;
            out_a[idx]   = a;
            out_cov[idx] = coverage[idx] + a;
        }
        __syncthreads();
    }
}

extern "C" void kernel_launch(void* const* d_in, const int* in_sizes, int n_in,
                              void* d_out, int out_size, void* d_ws, size_t ws_size,
                              hipStream_t stream) {
    const float* enc      = (const float*)d_in[0];
    const int*   mask     = (const int*)  d_in[1];
    const float* s        = (const float*)d_in[2];
    const float* coverage = (const float*)d_in[3];
    const float* hz       = (const float*)d_in[4];
    const float* W_s      = (const float*)d_in[5];
    const float* W_c      = (const float*)d_in[6];
    const float* b_c      = (const float*)d_in[7];
    const float* W_z      = (const float*)d_in[8];
    const float* v        = (const float*)d_in[9];

    float* out_a   = (float*)d_out;            // [B, S]
    float* out_cov = out_a + B_ * S_;          // [B, S]

    float* combined = (float*)d_ws;            // [B, H2]
    float* e_ws     = combined + B_ * H2_;     // [B, S]

    // Cooperative-safe grid: min(work, occupancy * CU count); grid-stride
    // loops inside make any clamp correct.
    int maxb = 0;
    hipOccupancyMaxActiveBlocksPerMultiprocessor(
        &maxb, reinterpret_cast<const void*>(fused_kernel), NTHR, 0);
    if (maxb <= 0) maxb = 4;
    int dev = 0;
    hipGetDevice(&dev);
    hipDeviceProp_t prop;
    int ncu = 256;
    if (hipGetDeviceProperties(&prop, dev) == hipSuccess) ncu = prop.multiProcessorCount;
    int nblk = maxb * ncu;
    if (nblk > WORK1) nblk = WORK1;

    void* args[] = {
        (void*)&enc, (void*)&mask, (void*)&s, (void*)&coverage, (void*)&hz,
        (void*)&W_s, (void*)&W_c, (void*)&b_c, (void*)&W_z, (void*)&v,
        (void*)&out_a, (void*)&out_cov, (void*)&combined, (void*)&e_ws
    };
    hipLaunchCooperativeKernel(reinterpret_cast<const void*>(fused_kernel),
                               dim3(nblk), dim3(NTHR), args, 0, stream);
}

// Round 5
// 38.512 us; speedup vs baseline: 8.1254x; 4.6554x over previous
//
#include <hip/hip_runtime.h>
#include <math.h>

#define B_     32
#define S_     1024
#define H2_    1024
#define TOPIC_ 256

__device__ __forceinline__ float fast_tanh(float x) {
    // tanh(x) = 1 - 2/(exp(2x)+1); saturates to +-1 at extremes.
    float e = __expf(2.0f * x);
    return 1.0f - 2.0f / (e + 1.0f);
}

// Kernel 1: combined[b][h] = sum_k s[b][k]*W_s[k][h] + sum_j hz[b][j]*W_z[j][h] + b_c[h]
// grid = (H2/32, B) = (32, 32), block = 256 (8 k-chunks x 32 h)
__global__ __launch_bounds__(256) void combined_kernel(
    const float* __restrict__ s,    // [B, H2]
    const float* __restrict__ hz,   // [B, TOPIC]
    const float* __restrict__ W_s,  // [H2, H2]  (in, out)
    const float* __restrict__ W_z,  // [TOPIC, H2]
    const float* __restrict__ b_c,  // [H2]
    float* __restrict__ combined)   // [B, H2]
{
    const int b  = blockIdx.y;
    const int hl = threadIdx.x & 31;
    const int h  = blockIdx.x * 32 + hl;
    const int kc = threadIdx.x >> 5;   // 0..7

    __shared__ float sx[H2_];
    __shared__ float zx[TOPIC_];
    for (int i = threadIdx.x; i < H2_; i += 256)    sx[i] = s[b * H2_ + i];
    for (int i = threadIdx.x; i < TOPIC_; i += 256) zx[i] = hz[b * TOPIC_ + i];
    __syncthreads();

    // 4 independent accumulators -> loads pipeline instead of serializing
    float a0 = 0.f, a1 = 0.f, a2 = 0.f, a3 = 0.f;
    {
        const int k0 = kc * 128;                       // 1024 / 8
        const float* Wp = W_s + (size_t)k0 * H2_ + h;
        #pragma unroll 4
        for (int i = 0; i < 128; i += 4) {
            a0 = fmaf(sx[k0 + i    ], Wp[(size_t)(i    ) * H2_], a0);
            a1 = fmaf(sx[k0 + i + 1], Wp[(size_t)(i + 1) * H2_], a1);
            a2 = fmaf(sx[k0 + i + 2], Wp[(size_t)(i + 2) * H2_], a2);
            a3 = fmaf(sx[k0 + i + 3], Wp[(size_t)(i + 3) * H2_], a3);
        }
    }
    {
        const int j0 = kc * 32;                        // 256 / 8
        const float* Wp = W_z + (size_t)j0 * H2_ + h;
        #pragma unroll 4
        for (int i = 0; i < 32; i += 4) {
            a0 = fmaf(zx[j0 + i    ], Wp[(size_t)(i    ) * H2_], a0);
            a1 = fmaf(zx[j0 + i + 1], Wp[(size_t)(i + 1) * H2_], a1);
            a2 = fmaf(zx[j0 + i + 2], Wp[(size_t)(i + 2) * H2_], a2);
            a3 = fmaf(zx[j0 + i + 3], Wp[(size_t)(i + 3) * H2_], a3);
        }
    }
    const float acc = (a0 + a1) + (a2 + a3);

    __shared__ float part[8][32];
    part[kc][hl] = acc;
    __syncthreads();
    if (kc == 0) {
        float r = b_c[h];
        #pragma unroll
        for (int c = 0; c < 8; ++c) r += part[c][hl];
        combined[b * H2_ + h] = r;
    }
}

// Kernel 2: e[row] = sum_h tanh(enc[row][h] + cov[row]*W_c[h] + combined[b][h]) * v[h]
// Wave-per-row: block = 256 (4 waves = 4 rows), grid = B*S/4 = 8192.
// No LDS, no __syncthreads; reduction is 6 shfl_xor within the wave.
__global__ __launch_bounds__(256, 4) void et_kernel(
    const float* __restrict__ enc,       // [B, S, H2]
    const float* __restrict__ coverage,  // [B, S]
    const float* __restrict__ W_c,       // [H2]
    const float* __restrict__ v,         // [H2]
    const float* __restrict__ combined,  // [B, H2]
    float* __restrict__ e_out)           // [B, S]
{
    const int tid  = threadIdx.x;
    const int row  = blockIdx.x * 4 + (tid >> 6);   // 4 rows per block
    const int b    = row >> 10;                     // S = 1024
    const int lane = tid & 63;

    const float4* e4   = (const float4*)enc + (size_t)row * (H2_ / 4);
    const float4* com4 = (const float4*)(combined + (size_t)b * H2_);
    const float4* wc4  = (const float4*)W_c;
    const float4* v4   = (const float4*)v;

    const float cov = coverage[row];

    float acc = 0.0f;
    #pragma unroll
    for (int i = 0; i < 4; ++i) {
        const int idx = lane + i * 64;              // float4 index within the row
        const float4 e  = e4[idx];
        const float4 w  = wc4[idx];
        const float4 vv = v4[idx];
        const float4 cb = com4[idx];
        acc = fmaf(fast_tanh(fmaf(cov, w.x, e.x) + cb.x), vv.x, acc);
        acc = fmaf(fast_tanh(fmaf(cov, w.y, e.y) + cb.y), vv.y, acc);
        acc = fmaf(fast_tanh(fmaf(cov, w.z, e.z) + cb.z), vv.z, acc);
        acc = fmaf(fast_tanh(fmaf(cov, w.w, e.w) + cb.w), vv.w, acc);
    }

    #pragma unroll
    for (int off = 32; off > 0; off >>= 1)
        acc += __shfl_xor(acc, off, 64);

    if (lane == 0)
        e_out[row] = acc;
}

// Kernel 3: masked softmax over S per batch + next_coverage
// grid = B, block = 256 (4 elems per thread)
__global__ __launch_bounds__(256) void softmax_kernel(
    const float* __restrict__ e_in,      // [B, S]
    const int*   __restrict__ mask,      // [B, S]
    const float* __restrict__ coverage,  // [B, S]
    float* __restrict__ a_out,           // [B, S]
    float* __restrict__ cov_out)         // [B, S]
{
    const int b   = blockIdx.x;
    const int tid = threadIdx.x;

    float ev[4];
    #pragma unroll
    for (int i = 0; i < 4; ++i) {
        const int idx = b * S_ + tid * 4 + i;
        float e = e_in[idx];
        if (mask[idx] == 0) e = -INFINITY;
        ev[i] = e;
    }

    float m = fmaxf(fmaxf(ev[0], ev[1]), fmaxf(ev[2], ev[3]));
    #pragma unroll
    for (int off = 1; off < 64; off <<= 1)
        m = fmaxf(m, __shfl_xor(m, off, 64));

    __shared__ float red[4];
    if ((tid & 63) == 0) red[tid >> 6] = m;
    __syncthreads();
    m = fmaxf(fmaxf(red[0], red[1]), fmaxf(red[2], red[3]));

    float p[4];
    float lsum = 0.0f;
    #pragma unroll
    for (int i = 0; i < 4; ++i) {
        p[i] = __expf(ev[i] - m);
        lsum += p[i];
    }
    #pragma unroll
    for (int off = 1; off < 64; off <<= 1)
        lsum += __shfl_xor(lsum, off, 64);

    __syncthreads();  // everyone done reading red[] from max phase
    if ((tid & 63) == 0) red[tid >> 6] = lsum;
    __syncthreads();
    const float tot = red[0] + red[1] + red[2] + red[3];
    const float inv = 1.0f / tot;

    #pragma unroll
    for (int i = 0; i < 4; ++i) {
        const int idx = b * S_ + tid * 4 + i;
        const float a = p[i] * inv;
        a_out[idx]   = a;
        cov_out[idx] = coverage[idx] + a;
    }
}

extern "C" void kernel_launch(void* const* d_in, const int* in_sizes, int n_in,
                              void* d_out, int out_size, void* d_ws, size_t ws_size,
                              hipStream_t stream) {
    const float* enc      = (const float*)d_in[0];
    const int*   mask     = (const int*)  d_in[1];
    const float* s        = (const float*)d_in[2];
    const float* coverage = (const float*)d_in[3];
    const float* hz       = (const float*)d_in[4];
    const float* W_s      = (const float*)d_in[5];
    const float* W_c      = (const float*)d_in[6];
    const float* b_c      = (const float*)d_in[7];
    const float* W_z      = (const float*)d_in[8];
    const float* v        = (const float*)d_in[9];

    float* out_a   = (float*)d_out;            // [B, S]
    float* out_cov = out_a + B_ * S_;          // [B, S]

    float* combined = (float*)d_ws;            // [B, H2]
    float* e_ws     = combined + B_ * H2_;     // [B, S]

    combined_kernel<<<dim3(H2_ / 32, B_), 256, 0, stream>>>(s, hz, W_s, W_z, b_c, combined);
    et_kernel<<<(B_ * S_) / 4, 256, 0, stream>>>(enc, coverage, W_c, v, combined, e_ws);
    softmax_kernel<<<B_, 256, 0, stream>>>(e_ws, mask, coverage, out_a, out_cov);
}